// Round 18
// baseline (51.163 us; speedup 1.0000x reference)
//
#include <hip/hip_runtime.h>
#include <hip/hip_bf16.h>

// GQA paged-prefill attention, MI355X gfx950.
// Causal mask j<=i over concat(past,new) => only first Q_LEN (=1024) gathered
// past tokens are live. Flash-attention over tokens 0..1023 of paged cache.
//
// R18 = R17 chain (single-buf LDS K/V, reg-dbuf staging, exp2 softmax,
// setprio) + R16's split grid: qt>=8 kv-halves (partials+combine), qt<8
// direct. Grid 768 -> ~3 independent blocks/CU (LDS 40KB, capacity 4) ->
// 3 independent wave-streams/SIMD, serial depth 16 -> 8.

#define Q_STRIDE 4096
// SCALE * log2(e): softmax computed in exp2 domain (v_exp_f32 is exp2).
#define SCALE2 0.1275179114285314f
#define RESCALE_THR 8.0f
#define KSW_TILE 16384                     // bytes per (hkv, jb) tile
#define VSW_OFF  (2 * 1024 * 1024)         // Vt tiles at +2MB
#define ACC1_OFF (4 * 1024 * 1024)         // half1 acc bf16: 32768 rows x 256B
#define ML0_OFF  (ACC1_OFF + 32768 * 256)  // half0 (m,l): 32768 x 8B
#define ML1_OFF  (ML0_OFF + 32768 * 8)     // half1 (m,l): 32768 x 8B

typedef short short8 __attribute__((ext_vector_type(8)));
typedef float f32x4 __attribute__((ext_vector_type(4)));
typedef unsigned short ushort_t;
typedef unsigned int uint_t;

__device__ __forceinline__ ushort_t f2bf(float f) {
    return __builtin_bit_cast(ushort_t, __float2bfloat16(f));
}
__device__ __forceinline__ uint_t pk2(float a, float b) {
    return (uint_t)f2bf(a) | ((uint_t)f2bf(b) << 16);
}
__device__ __forceinline__ float bf2f(ushort_t u) {
    uint_t x = ((uint_t)u) << 16;
    return __builtin_bit_cast(float, x);
}

// ---------------- prep: paged fp32 -> dense swizzled bf16 ----------------
__launch_bounds__(256)
__global__ void prep_kv(const float* __restrict__ kvc,
                        const int* __restrict__ bt,
                        char* __restrict__ wsb)
{
    __shared__ float sVt[64 * 128];
    const int blk = blockIdx.x;        // 128 blocks = hkv(8) x jb(16)
    const int hkv = blk >> 4;
    const int jb  = blk & 15;
    const int tid = threadIdx.x;
    char* kout = wsb + (size_t)(hkv * 16 + jb) * KSW_TILE;
    char* vout = wsb + VSW_OFF + (size_t)(hkv * 16 + jb) * KSW_TILE;

    // K: [t 64][d 128] bf16, 16B chunk c at byte t*256 + ((c*16)^((t&7)<<4))
#pragma unroll
    for (int i = 0; i < 4; ++i) {
        const int u = tid + i * 256;   // t(64) x c(16)
        const int t = u >> 4, c = u & 15;
        const int gtok = jb * 64 + t;
        const int page = bt[gtok >> 4];
        const float* src = kvc + (size_t)page * 32768 + (size_t)hkv * 2048
                         + (gtok & 15) * 128 + c * 8;
        float4 a = *(const float4*)src;
        float4 b = *(const float4*)(src + 4);
        uint4 p;
        p.x = pk2(a.x, a.y); p.y = pk2(a.z, a.w);
        p.z = pk2(b.x, b.y); p.w = pk2(b.z, b.w);
        *(uint4*)(kout + t * 256 + ((c * 16) ^ ((t & 7) << 4))) = p;
    }
    // V: coalesced fp32 read -> LDS ([t][d])
#pragma unroll
    for (int i = 0; i < 8; ++i) {
        const int u = tid + i * 256;   // t(64) x c4(32)
        const int t = u >> 5, c4 = u & 31;
        const int gtok = jb * 64 + t;
        const int page = bt[gtok >> 4];
        const float* src = kvc + (size_t)page * 32768 + 16384
                         + (size_t)hkv * 2048 + (gtok & 15) * 128 + c4 * 4;
        *(float4*)(sVt + t * 128 + c4 * 4) = *(const float4*)src;
    }
    __syncthreads();
    // Vt: [d 128][t 64] bf16, 16B chunk ch at byte (d*128+16*ch)^((d&7)<<4)
#pragma unroll
    for (int i = 0; i < 4; ++i) {
        const int u = tid + i * 256;   // d(128) x ch(8)
        const int d = u >> 3, ch = u & 7;
        float v[8];
#pragma unroll
        for (int k = 0; k < 8; ++k) v[k] = sVt[(8 * ch + k) * 128 + d];
        uint4 p;
        p.x = pk2(v[0], v[1]); p.y = pk2(v[2], v[3]);
        p.z = pk2(v[4], v[5]); p.w = pk2(v[6], v[7]);
        *(uint4*)(vout + ((d * 128 + 16 * ch) ^ ((d & 7) << 4))) = p;
    }
}

// ---------------- main attention ----------------
#define GLL16(G, L) __builtin_amdgcn_global_load_lds(                         \
    (const uint_t __attribute__((address_space(1)))*)(G),                     \
    (uint_t __attribute__((address_space(3)))*)(L), 16, 0, 0)

__launch_bounds__(256)
__global__ void attn_main(const float* __restrict__ q,
                          const char* __restrict__ kvbf,
                          float* __restrict__ out,
                          char* __restrict__ wsb)
{
    __shared__ __align__(16) char sK[16384];
    __shared__ __align__(16) char sV[16384];
    __shared__ __align__(16) char sP[4][2048];   // 40KB -> 4 blocks/CU cap

    const int bid = blockIdx.x;
    // bid<512: SPLIT halves of qt>=8 (long first). bid>=512: DIRECT qt<8.
    int qt, jb0, jb1, h, mode;         // mode 0 direct, 1 half0, 2 half1
    if (bid < 512) {
        const int half = bid & 1;
        const int idx  = bid >> 1;     // 0..255 carries (qt, h)
        qt  = 15 - (idx >> 5);         // 15..8
        h   = idx & 31;
        const int nt  = qt + 1;
        const int nt0 = (nt + 1) >> 1;
        jb0 = half ? nt0 : 0;
        jb1 = half ? nt : nt0;
        mode = half ? 2 : 1;
    } else {
        const int didx = bid - 512;
        qt  = 7 - (didx >> 5);         // 7..0 (long first)
        h   = didx & 31;
        jb0 = 0; jb1 = qt + 1;
        mode = 0;
    }
    const int hkv = h >> 2;
    const int tid  = threadIdx.x;
    const int w    = tid >> 6;
    const int lane = tid & 63;
    const int l15  = lane & 15;
    const int lhi  = lane >> 4;
    const int rg   = w;                // 16-row group

    // ---- Q fragments (SCALE2 folded -> exp2 domain)
    short8 qf[4];
    {
        const int qrow = qt * 64 + rg * 16 + l15;
        const float* qp = q + (size_t)qrow * Q_STRIDE + h * 128;
#pragma unroll
        for (int s = 0; s < 4; ++s) {
            const int d0 = s * 32 + lhi * 8;
            float4 a = *(const float4*)(qp + d0);
            float4 b = *(const float4*)(qp + d0 + 4);
            short8 v;
            v[0] = (short)f2bf(a.x * SCALE2); v[1] = (short)f2bf(a.y * SCALE2);
            v[2] = (short)f2bf(a.z * SCALE2); v[3] = (short)f2bf(a.w * SCALE2);
            v[4] = (short)f2bf(b.x * SCALE2); v[5] = (short)f2bf(b.y * SCALE2);
            v[6] = (short)f2bf(b.z * SCALE2); v[7] = (short)f2bf(b.w * SCALE2);
            qf[s] = v;
        }
    }

    f32x4 acc[8];
#pragma unroll
    for (int n2 = 0; n2 < 8; ++n2) acc[n2] = (f32x4){0.f, 0.f, 0.f, 0.f};
    float m_run[4]  = {-1e30f, -1e30f, -1e30f, -1e30f};
    float l_part[4] = {0.f, 0.f, 0.f, 0.f};

    // prologue: tile jb0 -> LDS via DMA, one full drain
    {
        const char* b0 = kvbf + (size_t)(hkv * 16 + jb0) * KSW_TILE
                       + w * 4096 + lane * 16;
#pragma unroll
        for (int i = 0; i < 4; ++i) {
            GLL16(b0 + i * 1024,           sK + w * 4096 + i * 1024);
            GLL16(b0 + VSW_OFF + i * 1024, sV + w * 4096 + i * 1024);
        }
    }
    __syncthreads();

    char* pb = sP[w];
    for (int jb = jb0; jb < jb1; ++jb) {
        const bool pf = (jb + 1 < jb1);

        // ---- issue next tile's loads to NAMED registers (land under compute)
        float4 kr0, kr1, kr2, kr3, vr0, vr1, vr2, vr3;
        if (pf) {
            const char* nb = kvbf + (size_t)(hkv * 16 + jb + 1) * KSW_TILE
                           + w * 4096 + lane * 16;
            kr0 = *(const float4*)(nb);
            kr1 = *(const float4*)(nb + 1024);
            kr2 = *(const float4*)(nb + 2048);
            kr3 = *(const float4*)(nb + 3072);
            const char* nv = nb + VSW_OFF;
            vr0 = *(const float4*)(nv);
            vr1 = *(const float4*)(nv + 1024);
            vr2 = *(const float4*)(nv + 2048);
            vr3 = *(const float4*)(nv + 3072);
        }

        // ---- S = Q K^T
        f32x4 sacc[4];
#pragma unroll
        for (int n = 0; n < 4; ++n) sacc[n] = (f32x4){0.f, 0.f, 0.f, 0.f};
        __builtin_amdgcn_s_setprio(1);
#pragma unroll
        for (int s = 0; s < 4; ++s) {
#pragma unroll
            for (int n = 0; n < 4; ++n) {
                const int tok = n * 16 + l15;
                const uint_t byte = (uint_t)(tok * 256)
                    + (((uint_t)((s * 32 + lhi * 8) * 2)) ^ ((uint_t)((tok & 7) << 4)));
                short8 kb = *(const short8*)(sK + byte);
                sacc[n] = __builtin_amdgcn_mfma_f32_16x16x32_bf16(qf[s], kb, sacc[n], 0, 0, 0);
            }
        }
        __builtin_amdgcn_s_setprio(0);

        // ---- softmax (exp2 domain) with deferred max
        const bool diag = (jb == qt);
        if (diag) {
#pragma unroll
            for (int n = 0; n < 4; ++n)
#pragma unroll
                for (int j = 0; j < 4; ++j) {
                    const int tok = jb * 64 + n * 16 + l15;
                    const int qg  = qt * 64 + rg * 16 + lhi * 4 + j;
                    if (tok > qg) sacc[n][j] = -1e30f;
                }
        }
#pragma unroll
        for (int j = 0; j < 4; ++j) {
            float lmax = fmaxf(fmaxf(sacc[0][j], sacc[1][j]),
                               fmaxf(sacc[2][j], sacc[3][j]));
            if (__any(lmax > m_run[j] + RESCALE_THR)) {
                float mt = lmax;
#pragma unroll
                for (int off = 1; off < 16; off <<= 1)
                    mt = fmaxf(mt, __shfl_xor(mt, off));
                const float mn = fmaxf(m_run[j], mt);
                const float alpha = exp2f(m_run[j] - mn);
                m_run[j] = mn;
                l_part[j] *= alpha;
#pragma unroll
                for (int n2 = 0; n2 < 8; ++n2) acc[n2][j] *= alpha;
            }
            float ls = 0.f;
#pragma unroll
            for (int n = 0; n < 4; ++n) {
                float p = exp2f(sacc[n][j] - m_run[j]);
                sacc[n][j] = p;
                ls += p;
            }
            l_part[j] += ls;
        }

        // ---- P -> per-wave LDS (A-fragment relayout); same-wave lgkmcnt
#pragma unroll
        for (int n = 0; n < 4; ++n)
#pragma unroll
            for (int j = 0; j < 4; ++j) {
                const int r = lhi * 4 + j;
                const uint_t byte = (uint_t)(r * 128)
                    + (((uint_t)((n * 16 + l15) * 2)) ^ ((uint_t)((r & 7) << 4)));
                *(ushort_t*)(pb + byte) = f2bf(sacc[n][j]);
            }

        // ---- O += P V
        __builtin_amdgcn_s_setprio(1);
#pragma unroll
        for (int s2 = 0; s2 < 2; ++s2) {
            const uint_t pbyte = (uint_t)(l15 * 128)
                + (((uint_t)((s2 * 32 + lhi * 8) * 2)) ^ ((uint_t)((l15 & 7) << 4)));
            short8 pa = *(const short8*)(pb + pbyte);
#pragma unroll
            for (int n2 = 0; n2 < 8; ++n2) {
                const int dim = n2 * 16 + l15;
                const uint_t vbyte = (uint_t)(dim * 128)
                    + (((uint_t)((s2 * 32 + lhi * 8) * 2)) ^ ((uint_t)((dim & 7) << 4)));
                short8 vbf = *(const short8*)(sV + vbyte);
                acc[n2] = __builtin_amdgcn_mfma_f32_16x16x32_bf16(pa, vbf, acc[n2], 0, 0, 0);
            }
        }
        __builtin_amdgcn_s_setprio(0);

        if (pf) {
            __syncthreads();   // all waves done reading sK/sV for tile jb
            *(float4*)(sK + w * 4096 + lane * 16)        = kr0;
            *(float4*)(sK + w * 4096 + 1024 + lane * 16) = kr1;
            *(float4*)(sK + w * 4096 + 2048 + lane * 16) = kr2;
            *(float4*)(sK + w * 4096 + 3072 + lane * 16) = kr3;
            *(float4*)(sV + w * 4096 + lane * 16)        = vr0;
            *(float4*)(sV + w * 4096 + 1024 + lane * 16) = vr1;
            *(float4*)(sV + w * 4096 + 2048 + lane * 16) = vr2;
            *(float4*)(sV + w * 4096 + 3072 + lane * 16) = vr3;
            __syncthreads();   // tile jb+1 visible to all
        }
    }

    // ---- epilogue
#pragma unroll
    for (int j = 0; j < 4; ++j) {
        float lsum = l_part[j];
#pragma unroll
        for (int off = 1; off < 16; off <<= 1)
            lsum += __shfl_xor(lsum, off);
        const int row64 = rg * 16 + lhi * 4 + j;
        const int qg    = qt * 64 + row64;
        if (mode == 0) {
            const float inv = 1.0f / lsum;
            float* dst = out + (size_t)qg * Q_STRIDE + h * 128;
#pragma unroll
            for (int n2 = 0; n2 < 8; ++n2)
                dst[n2 * 16 + l15] = acc[n2][j] * inv;
        } else {
            const int idx = (qt * 32 + h) * 64 + row64;
            if (mode == 1) {
                float* dst = out + (size_t)qg * Q_STRIDE + h * 128;
#pragma unroll
                for (int n2 = 0; n2 < 8; ++n2)
                    dst[n2 * 16 + l15] = acc[n2][j];   // unnormalized
                if (l15 == 0) {
                    float* ml = (float*)(wsb + ML0_OFF) + (size_t)idx * 2;
                    ml[0] = m_run[j]; ml[1] = lsum;
                }
            } else {
                ushort_t* dst = (ushort_t*)(wsb + ACC1_OFF) + (size_t)idx * 128;
#pragma unroll
                for (int n2 = 0; n2 < 8; ++n2)
                    dst[n2 * 16 + l15] = f2bf(acc[n2][j]);
                if (l15 == 0) {
                    float* ml = (float*)(wsb + ML1_OFF) + (size_t)idx * 2;
                    ml[0] = m_run[j]; ml[1] = lsum;
                }
            }
        }
    }
}

// ---------------- combine (qt>=8 rows only; m in exp2 domain) -------------
__launch_bounds__(256)
__global__ void attn_combine(float* __restrict__ out, const char* __restrict__ wsb)
{
    const int pid = blockIdx.x;           // 256 = (qt-8)(8) x h(32)
    const int qt = 8 + (pid >> 5);
    const int h  = pid & 31;
    const int tid = threadIdx.x;
    const int d4  = (tid & 31) * 4;
    const float* ml0b = (const float*)(wsb + ML0_OFF);
    const float* ml1b = (const float*)(wsb + ML1_OFF);
    const ushort_t* a1b = (const ushort_t*)(wsb + ACC1_OFF);

#pragma unroll
    for (int p = 0; p < 8; ++p) {
        const int r = (tid >> 5) + p * 8;            // row 0..63
        const size_t idx = (size_t)(qt * 32 + h) * 64 + r;
        const float m1 = ml0b[idx * 2], l1 = ml0b[idx * 2 + 1];
        const float m2 = ml1b[idx * 2], l2 = ml1b[idx * 2 + 1];
        const float m  = fmaxf(m1, m2);
        const float a1 = exp2f(m1 - m), a2 = exp2f(m2 - m);
        const float inv = 1.0f / (l1 * a1 + l2 * a2);
        float* o = out + (size_t)(qt * 64 + r) * Q_STRIDE + h * 128 + d4;
        const ushort_t* y4 = a1b + idx * 128 + d4;
        float4 x = *(const float4*)o;
        x.x = (x.x * a1 + bf2f(y4[0]) * a2) * inv;
        x.y = (x.y * a1 + bf2f(y4[1]) * a2) * inv;
        x.z = (x.z * a1 + bf2f(y4[2]) * a2) * inv;
        x.w = (x.w * a1 + bf2f(y4[3]) * a2) * inv;
        *(float4*)o = x;
    }
}

extern "C" void kernel_launch(void* const* d_in, const int* in_sizes, int n_in,
                              void* d_out, int out_size, void* d_ws, size_t ws_size,
                              hipStream_t stream) {
    const float* q   = (const float*)d_in[0];
    // d_in[1] (k) and d_in[2] (v) are dead under the reference's causal mask.
    const float* kvc = (const float*)d_in[3];
    const int*   bt  = (const int*)d_in[4];
    float* out = (float*)d_out;
    char*  wsb = (char*)d_ws;
    prep_kv<<<dim3(128), dim3(256), 0, stream>>>(kvc, bt, wsb);
    attn_main<<<dim3(768), dim3(256), 0, stream>>>(q, wsb, out, wsb);
    attn_combine<<<dim3(256), dim3(256), 0, stream>>>(out, wsb);
}

// Round 19
// 44.737 us; speedup vs baseline: 1.1436x; 1.1436x over previous
//
#include <hip/hip_runtime.h>
#include <hip/hip_bf16.h>

// GQA paged-prefill attention, MI355X gfx950.
// Causal mask j<=i over concat(past,new) => only first Q_LEN (=1024) gathered
// past tokens are live. Flash-attention over tokens 0..1023 of paged cache.
//
// R19 = R13 + lagged-PV software pipeline (T15): PV of tile j-1 runs as a
// REGISTER-ONLY MFMA cluster in iter j (P frags + V frags carried in regs),
// overlapping softmax_j's VALU chain. PV leaves the pre-barrier critical
// path. exp2-domain softmax. Counted-vmcnt staging as R13.

#define NUM_HEADS 32
#define HEAD_DIM 128
#define Q_STRIDE 4096
// SCALE * log2(e): softmax computed in exp2 domain (v_exp_f32 is exp2).
#define SCALE2 0.1275179114285314f
#define RESCALE_THR 8.0f
#define KSW_TILE 16384                 // bytes per (hkv, jb) tile
#define VSW_OFF (2 * 1024 * 1024)      // Vt tiles start 2MB into ws

typedef short short8 __attribute__((ext_vector_type(8)));
typedef float f32x4 __attribute__((ext_vector_type(4)));
typedef unsigned short ushort_t;
typedef unsigned int uint_t;

__device__ __forceinline__ ushort_t f2bf(float f) {
    return __builtin_bit_cast(ushort_t, __float2bfloat16(f));
}
__device__ __forceinline__ uint_t pk2(float a, float b) {
    return (uint_t)f2bf(a) | ((uint_t)f2bf(b) << 16);
}

// ---------------- prep: paged fp32 -> dense swizzled bf16 ----------------
__launch_bounds__(256)
__global__ void prep_kv(const float* __restrict__ kvc,
                        const int* __restrict__ bt,
                        char* __restrict__ wsb)
{
    __shared__ float sVt[64 * 128];
    const int blk = blockIdx.x;        // 128 blocks = hkv(8) x jb(16)
    const int hkv = blk >> 4;
    const int jb  = blk & 15;
    const int tid = threadIdx.x;
    char* kout = wsb + (size_t)(hkv * 16 + jb) * KSW_TILE;
    char* vout = wsb + VSW_OFF + (size_t)(hkv * 16 + jb) * KSW_TILE;

    // K: [t 64][d 128] bf16, 16B chunk c at byte t*256 + ((c*16)^((t&7)<<4))
#pragma unroll
    for (int i = 0; i < 4; ++i) {
        const int u = tid + i * 256;   // t(64) x c(16)
        const int t = u >> 4, c = u & 15;
        const int gtok = jb * 64 + t;
        const int page = bt[gtok >> 4];
        const float* src = kvc + (size_t)page * 32768 + (size_t)hkv * 2048
                         + (gtok & 15) * 128 + c * 8;
        float4 a = *(const float4*)src;
        float4 b = *(const float4*)(src + 4);
        uint4 p;
        p.x = pk2(a.x, a.y); p.y = pk2(a.z, a.w);
        p.z = pk2(b.x, b.y); p.w = pk2(b.z, b.w);
        *(uint4*)(kout + t * 256 + ((c * 16) ^ ((t & 7) << 4))) = p;
    }
    // V: coalesced fp32 read -> LDS ([t][d])
#pragma unroll
    for (int i = 0; i < 8; ++i) {
        const int u = tid + i * 256;   // t(64) x c4(32)
        const int t = u >> 5, c4 = u & 31;
        const int gtok = jb * 64 + t;
        const int page = bt[gtok >> 4];
        const float* src = kvc + (size_t)page * 32768 + 16384
                         + (size_t)hkv * 2048 + (gtok & 15) * 128 + c4 * 4;
        *(float4*)(sVt + t * 128 + c4 * 4) = *(const float4*)src;
    }
    __syncthreads();
    // Vt: [d 128][t 64] bf16, 16B chunk ch at byte (d*128+16*ch)^((d&7)<<4)
#pragma unroll
    for (int i = 0; i < 4; ++i) {
        const int u = tid + i * 256;   // d(128) x ch(8)
        const int d = u >> 3, ch = u & 7;
        float v[8];
#pragma unroll
        for (int k = 0; k < 8; ++k) v[k] = sVt[(8 * ch + k) * 128 + d];
        uint4 p;
        p.x = pk2(v[0], v[1]); p.y = pk2(v[2], v[3]);
        p.z = pk2(v[4], v[5]); p.w = pk2(v[6], v[7]);
        *(uint4*)(vout + ((d * 128 + 16 * ch) ^ ((d & 7) << 4))) = p;
    }
}

// ---------------- main attention ----------------
#define GLL16(G, L) __builtin_amdgcn_global_load_lds(                         \
    (const uint_t __attribute__((address_space(1)))*)(G),                     \
    (uint_t __attribute__((address_space(3)))*)(L), 16, 0, 0)

// Stage tile JB: 8 gll per wave (4KB K slice + 4KB V slice).
#define STAGE(JB, KB, VB) {                                                   \
    const char* ks = kvbf + (size_t)(hkv * 16 + (JB)) * KSW_TILE              \
                   + w * 4096 + lane * 16;                                    \
    const char* vs = ks + VSW_OFF;                                            \
    _Pragma("unroll")                                                         \
    for (int i = 0; i < 4; ++i) {                                             \
        GLL16(ks + i * 1024, (KB) + w * 4096 + i * 1024);                     \
        GLL16(vs + i * 1024, (VB) + w * 4096 + i * 1024);                     \
    }                                                                         \
}

__launch_bounds__(256)
__global__ void attn_main(const float* __restrict__ q,
                          const char* __restrict__ kvbf,
                          float* __restrict__ out)
{
    __shared__ __align__(16) char sK[2][16384];
    __shared__ __align__(16) char sV[2][16384];
    __shared__ __align__(16) char sP[4][2048];

    const int bid = blockIdx.x;
    const int h   = bid & 31;
    const int qt  = 15 - (bid >> 5);   // long blocks first
    const int hkv = h >> 2;
    const int tid  = threadIdx.x;
    const int w    = tid >> 6;
    const int lane = tid & 63;
    const int l15  = lane & 15;
    const int lhi  = lane >> 4;

    // ---- Q fragments (SCALE2 folded -> exp2 domain)
    short8 qf[4];
    {
        const int qrow = qt * 64 + w * 16 + l15;
        const float* qp = q + (size_t)qrow * Q_STRIDE + h * HEAD_DIM;
#pragma unroll
        for (int s = 0; s < 4; ++s) {
            const int d0 = s * 32 + lhi * 8;
            float4 a = *(const float4*)(qp + d0);
            float4 b = *(const float4*)(qp + d0 + 4);
            short8 v;
            v[0] = (short)f2bf(a.x * SCALE2); v[1] = (short)f2bf(a.y * SCALE2);
            v[2] = (short)f2bf(a.z * SCALE2); v[3] = (short)f2bf(a.w * SCALE2);
            v[4] = (short)f2bf(b.x * SCALE2); v[5] = (short)f2bf(b.y * SCALE2);
            v[6] = (short)f2bf(b.z * SCALE2); v[7] = (short)f2bf(b.w * SCALE2);
            qf[s] = v;
        }
    }

    f32x4 acc[8];
#pragma unroll
    for (int n2 = 0; n2 < 8; ++n2) acc[n2] = (f32x4){0.f, 0.f, 0.f, 0.f};
    float m_run[4]  = {-1e30f, -1e30f, -1e30f, -1e30f};
    float l_part[4] = {0.f, 0.f, 0.f, 0.f};

    // lagged-PV register state: P fragments + V fragments of tile j-1
    short8 pap0, pap1;
    short8 vbp[2][8];

    // prologue: tile 0 -> buf 0, full drain once
    STAGE(0, sK[0], sV[0])
    __syncthreads();

    char* pb = sP[w];
    for (int jb = 0; jb <= qt; ++jb) {
        const int cur = jb & 1;
        char* kbuf = sK[cur];
        char* vbuf = sV[cur];
        const bool pf = (jb < qt);
        if (pf) {
            STAGE(jb + 1, sK[cur ^ 1], sV[cur ^ 1])
            asm volatile("s_waitcnt vmcnt(8)" ::: "memory");
        } else {
            asm volatile("s_waitcnt vmcnt(0)" ::: "memory");
        }
        __builtin_amdgcn_sched_barrier(0);
        __builtin_amdgcn_s_barrier();
        __builtin_amdgcn_sched_barrier(0);

        __builtin_amdgcn_s_setprio(1);
        // ---- lagged PV_{j-1}: register-only MFMAs, fills the MFMA pipe
        // while this tile's K ds_reads are in flight; adds into acc scaled
        // for m_{j-1} BEFORE this tile's rescale (correct online-softmax).
        if (jb > 0) {
#pragma unroll
            for (int n2 = 0; n2 < 8; ++n2) {
                acc[n2] = __builtin_amdgcn_mfma_f32_16x16x32_bf16(pap0, vbp[0][n2], acc[n2], 0, 0, 0);
                acc[n2] = __builtin_amdgcn_mfma_f32_16x16x32_bf16(pap1, vbp[1][n2], acc[n2], 0, 0, 0);
            }
        }

        // ---- S = Q K^T
        f32x4 sacc[4];
#pragma unroll
        for (int n = 0; n < 4; ++n) sacc[n] = (f32x4){0.f, 0.f, 0.f, 0.f};
#pragma unroll
        for (int s = 0; s < 4; ++s) {
#pragma unroll
            for (int n = 0; n < 4; ++n) {
                const int tok = n * 16 + l15;
                const uint_t byte = (uint_t)(tok * 256)
                    + (((uint_t)((s * 32 + lhi * 8) * 2)) ^ ((uint_t)((tok & 7) << 4)));
                short8 kb = *(const short8*)(kbuf + byte);
                sacc[n] = __builtin_amdgcn_mfma_f32_16x16x32_bf16(qf[s], kb, sacc[n], 0, 0, 0);
            }
        }
        __builtin_amdgcn_s_setprio(0);

        // ---- softmax (exp2 domain) with deferred max; VALU chain overlaps
        // the lagged-PV MFMAs still draining (no data dep until rescale).
        const bool diag = (jb == qt);
        if (diag) {
#pragma unroll
            for (int n = 0; n < 4; ++n)
#pragma unroll
                for (int j = 0; j < 4; ++j) {
                    const int tok = jb * 64 + n * 16 + l15;
                    const int qg  = qt * 64 + w * 16 + lhi * 4 + j;
                    if (tok > qg) sacc[n][j] = -1e30f;
                }
        }
#pragma unroll
        for (int j = 0; j < 4; ++j) {
            float lmax = fmaxf(fmaxf(sacc[0][j], sacc[1][j]),
                               fmaxf(sacc[2][j], sacc[3][j]));
            if (__any(lmax > m_run[j] + RESCALE_THR)) {
                float mt = lmax;
#pragma unroll
                for (int off = 1; off < 16; off <<= 1)
                    mt = fmaxf(mt, __shfl_xor(mt, off));
                const float mn = fmaxf(m_run[j], mt);
                const float alpha = exp2f(m_run[j] - mn);
                m_run[j] = mn;
                l_part[j] *= alpha;
#pragma unroll
                for (int n2 = 0; n2 < 8; ++n2) acc[n2][j] *= alpha;
            }
            float ls = 0.f;
#pragma unroll
            for (int n = 0; n < 4; ++n) {
                float p = exp2f(sacc[n][j] - m_run[j]);
                sacc[n][j] = p;
                ls += p;
            }
            l_part[j] += ls;
        }

        // ---- P_j -> per-wave LDS (A-fragment relayout); same-wave lgkmcnt
#pragma unroll
        for (int n = 0; n < 4; ++n)
#pragma unroll
            for (int j = 0; j < 4; ++j) {
                const int r = lhi * 4 + j;
                const uint_t byte = (uint_t)(r * 128)
                    + (((uint_t)((n * 16 + l15) * 2)) ^ ((uint_t)((r & 7) << 4)));
                *(ushort_t*)(pb + byte) = f2bf(sacc[n][j]);
            }

        // ---- pull P_j A-fragments and V_j fragments into registers for the
        // NEXT iteration's lagged PV (no MFMA consumes them this iter).
        {
            const uint_t pbyte0 = (uint_t)(l15 * 128)
                + (((uint_t)((lhi * 8) * 2)) ^ ((uint_t)((l15 & 7) << 4)));
            pap0 = *(const short8*)(pb + pbyte0);
            const uint_t pbyte1 = (uint_t)(l15 * 128)
                + (((uint_t)((32 + lhi * 8) * 2)) ^ ((uint_t)((l15 & 7) << 4)));
            pap1 = *(const short8*)(pb + pbyte1);
        }
#pragma unroll
        for (int s2 = 0; s2 < 2; ++s2)
#pragma unroll
            for (int n2 = 0; n2 < 8; ++n2) {
                const int dim = n2 * 16 + l15;
                const uint_t vbyte = (uint_t)(dim * 128)
                    + (((uint_t)((s2 * 32 + lhi * 8) * 2)) ^ ((uint_t)((dim & 7) << 4)));
                vbp[s2][n2] = *(const short8*)(vbuf + vbyte);
            }

        if (pf) {
            // my V/P ds_reads must complete before any wave's next STAGE
            // overwrites this buffer pair
            asm volatile("s_waitcnt lgkmcnt(0)" ::: "memory");
            __builtin_amdgcn_sched_barrier(0);
            __builtin_amdgcn_s_barrier();
            __builtin_amdgcn_sched_barrier(0);
        }
    }

    // ---- final lagged PV (last tile)
    asm volatile("s_waitcnt lgkmcnt(0)" ::: "memory");
    __builtin_amdgcn_sched_barrier(0);
#pragma unroll
    for (int n2 = 0; n2 < 8; ++n2) {
        acc[n2] = __builtin_amdgcn_mfma_f32_16x16x32_bf16(pap0, vbp[0][n2], acc[n2], 0, 0, 0);
        acc[n2] = __builtin_amdgcn_mfma_f32_16x16x32_bf16(pap1, vbp[1][n2], acc[n2], 0, 0, 0);
    }

    // ---- epilogue: reduce per-lane l across 16-lane row group, store
#pragma unroll
    for (int j = 0; j < 4; ++j) {
        float lsum = l_part[j];
#pragma unroll
        for (int off = 1; off < 16; off <<= 1)
            lsum += __shfl_xor(lsum, off);
        const float inv = 1.0f / lsum;
        const int qg = qt * 64 + w * 16 + lhi * 4 + j;
        float* dst = out + (size_t)qg * Q_STRIDE + h * HEAD_DIM;
#pragma unroll
        for (int n2 = 0; n2 < 8; ++n2)
            dst[n2 * 16 + l15] = acc[n2][j] * inv;
    }
}

extern "C" void kernel_launch(void* const* d_in, const int* in_sizes, int n_in,
                              void* d_out, int out_size, void* d_ws, size_t ws_size,
                              hipStream_t stream) {
    const float* q   = (const float*)d_in[0];
    // d_in[1] (k) and d_in[2] (v) are dead under the reference's causal mask.
    const float* kvc = (const float*)d_in[3];
    const int*   bt  = (const int*)d_in[4];
    float* out = (float*)d_out;
    char*  wsb = (char*)d_ws;
    prep_kv<<<dim3(128), dim3(256), 0, stream>>>(kvc, bt, wsb);
    attn_main<<<dim3(512), dim3(256), 0, stream>>>(q, wsb, out);
}